// Round 1
// baseline (388.891 us; speedup 1.0000x reference)
//
#include <hip/hip_runtime.h>

typedef unsigned int u32;
typedef unsigned short u16;
typedef __bf16 bf16x8 __attribute__((ext_vector_type(8)));
typedef float f32x4 __attribute__((ext_vector_type(4)));

#define D 2048           // D_IN == D_MODEL == S == 2048
#define BATCH 2
#define BM 256
#define BN 128
#define BK 64
#define NT (D / BK)          // 32 K-tiles
#define ABUF (BM * BK)       // 16384 u16 = 32 KB
#define BBUF (BN * BK)       // 8192  u16 = 16 KB
#define BUFSZ (ABUF + BBUF)  // 24576 u16 = 48 KB per buffer, x3 = 144 KB

// ---------- helpers ----------
__device__ __forceinline__ u32 bf16rne(float f) {
  u32 u = __builtin_bit_cast(u32, f);
  return (u + 0x7fffu + ((u >> 16) & 1u)) >> 16;
}
__device__ __forceinline__ u32 pk2(float lo, float hi) {
  return bf16rne(lo) | (bf16rne(hi) << 16);
}
__device__ __forceinline__ void async16(const u16* g, u16* l) {
  __builtin_amdgcn_global_load_lds(
      (const __attribute__((address_space(1))) void*)g,
      (__attribute__((address_space(3))) void*)l, 16, 0, 0);
}

// ---------- kernel 1: x fp32 -> bf16 (unchanged, verified) ----------
__global__ void __launch_bounds__(256) prep_x_kernel(const float* __restrict__ x,
                                                     u16* __restrict__ o) {
  size_t t = (size_t)blockIdx.x * 256 + threadIdx.x;
  const float4* x4 = (const float4*)x;
  float4 a = x4[2 * t], b = x4[2 * t + 1];
  ((uint4*)o)[t] = make_uint4(pk2(a.x, a.y), pk2(a.z, a.w),
                              pk2(b.x, b.y), pk2(b.z, b.w));
}

// ---------- kernel 2: wt[b][n][k] = bf16(p0*W[i0][k][n] + p1*W[i1][k][n]) ----------
__global__ void __launch_bounds__(256) prep_w_kernel(const float* __restrict__ W,
                                                     const int* __restrict__ sidx,
                                                     const float* __restrict__ sprob,
                                                     u16* __restrict__ wt) {
  const int b = blockIdx.z;
  const int n = blockIdx.x * 256 + threadIdx.x;
  const int k0 = blockIdx.y * 32;
  const int i0 = sidx[2 * b], i1 = sidx[2 * b + 1];
  const float p0 = sprob[2 * b], p1 = sprob[2 * b + 1];
  const float* w0 = W + ((size_t)i0 * D + k0) * D + n;
  const float* w1 = W + ((size_t)i1 * D + k0) * D + n;
  u32 r[16];
#pragma unroll
  for (int kk = 0; kk < 16; ++kk) {
    float a0 = w0[(size_t)(2 * kk) * D],     c0 = w1[(size_t)(2 * kk) * D];
    float a1 = w0[(size_t)(2 * kk + 1) * D], c1 = w1[(size_t)(2 * kk + 1) * D];
    r[kk] = pk2(p0 * a0 + p1 * c0, p0 * a1 + p1 * c1);
  }
  uint4* dst = (uint4*)(wt + ((size_t)b * D + n) * D + k0);
#pragma unroll
  for (int q = 0; q < 4; ++q)
    dst[q] = make_uint4(r[4 * q], r[4 * q + 1], r[4 * q + 2], r[4 * q + 3]);
}

// ---------- kernel 3: out[b] = xb[b] @ wt[b]^T + bsel[b] ----------
// 256x128 tile, BK=64, 512 threads = 8 waves (2M x 4N), per-wave 128x32 output.
// Triple-buffered LDS (144 KB), phased schedule with counted vmcnt(6) (never
// drained in-loop), XOR-swizzled k-chunks (pre-swizzled global source + linear
// global_load_lds dest + swizzled ds_read), setprio around MFMA clusters.
__global__ void __launch_bounds__(512, 2)
gemm_kernel(const u16* __restrict__ xb, const u16* __restrict__ wt,
            const float* __restrict__ bias, const int* __restrict__ sidx,
            const float* __restrict__ sprob, float* __restrict__ out) {
  extern __shared__ __align__(16) u16 LL[];

  const int b  = blockIdx.z;
  const int n0 = blockIdx.x * BN;
  const int m0 = blockIdx.y * BM;
  const int tid  = threadIdx.x;
  const int lane = tid & 63;
  const int wid  = tid >> 6;
  const int wm = (wid >> 2) * 128;  // 2 wave-rows over 256 m
  const int wn = (wid & 3) * 32;    // 4 wave-cols over 128 n
  const int fm = lane & 15;
  const int q  = lane >> 4;         // 16B k-chunk index within a 32-k plane

  const u16* Ab = xb + (size_t)b * D * D;
  const u16* Bb = wt + (size_t)b * D * D;

  // staging: inst i covers granules g = i*512 + tid; row = g>>3, phys slot = g&7.
  // LDS dest is linear; the XOR swizzle is applied on the SOURCE k-chunk (m173).
  const int srow  = tid >> 3;                   // row within 64-row inst stripe
  const int sslot = (tid & 7) ^ (srow & 7);     // pre-swizzled logical k-chunk
  const u16* srcp[6];
#pragma unroll
  for (int i = 0; i < 4; ++i)
    srcp[i] = Ab + (size_t)(m0 + i * 64 + srow) * D + sslot * 8;
#pragma unroll
  for (int i = 0; i < 2; ++i)
    srcp[4 + i] = Bb + (size_t)(n0 + i * 64 + srow) * D + sslot * 8;

  const int wuni = (tid & ~63) * 8;  // wave-uniform LDS granule base (elems)

  auto stageInst = [&](int buf, int i) {
    async16(srcp[i], LL + buf * BUFSZ + i * 4096 + wuni);
  };

  // fragment read offsets (elements), XOR-swizzled to match the staged layout
  int offA[8][2], offB[2][2];
#pragma unroll
  for (int m = 0; m < 8; ++m) {
    const int row = wm + m * 16 + fm;
#pragma unroll
    for (int ks = 0; ks < 2; ++ks)
      offA[m][ks] = row * 64 + (((ks * 4 + q) ^ (row & 7)) * 8);
  }
#pragma unroll
  for (int n = 0; n < 2; ++n) {
    const int row = wn + n * 16 + fm;
#pragma unroll
    for (int ks = 0; ks < 2; ++ks)
      offB[n][ks] = ABUF + row * 64 + (((ks * 4 + q) ^ (row & 7)) * 8);
  }

  f32x4 acc[8][2] = {};

  // prologue: stage tiles 0,1 into bufs 0,1; wait only for tile 0 (vmcnt(6))
#pragma unroll
  for (int i = 0; i < 6; ++i) stageInst(0, i);
#pragma unroll
  for (int i = 0; i < 6; ++i) srcp[i] += BK;
#pragma unroll
  for (int i = 0; i < 6; ++i) stageInst(1, i);
#pragma unroll
  for (int i = 0; i < 6; ++i) srcp[i] += BK;
  asm volatile("s_waitcnt vmcnt(6)" ::: "memory");
  __builtin_amdgcn_s_barrier();

  int cur = 0;
#pragma unroll 1
  for (int t = 0; t < NT; ++t) {
    const u16* Lc = LL + cur * BUFSZ;
    int nst = cur + 2; if (nst >= 3) nst -= 3;
    const bool doStage = (t + 2 < NT);

    bf16x8 af[8], bfr[2];

    // ---- phase 0 (ks = 0) ----
#pragma unroll
    for (int m = 0; m < 8; ++m) af[m] = *(const bf16x8*)(Lc + offA[m][0]);
#pragma unroll
    for (int n = 0; n < 2; ++n) bfr[n] = *(const bf16x8*)(Lc + offB[n][0]);
    if (doStage) { stageInst(nst, 0); stageInst(nst, 1); stageInst(nst, 2); }
    __builtin_amdgcn_s_barrier();
    asm volatile("s_waitcnt lgkmcnt(0)" ::: "memory");
    __builtin_amdgcn_sched_barrier(0);
    __builtin_amdgcn_s_setprio(1);
#pragma unroll
    for (int m = 0; m < 8; ++m)
#pragma unroll
      for (int n = 0; n < 2; ++n)
        acc[m][n] = __builtin_amdgcn_mfma_f32_16x16x32_bf16(af[m], bfr[n],
                                                            acc[m][n], 0, 0, 0);
    __builtin_amdgcn_s_setprio(0);
    __builtin_amdgcn_s_barrier();

    // ---- phase 1 (ks = 1) ----
#pragma unroll
    for (int m = 0; m < 8; ++m) af[m] = *(const bf16x8*)(Lc + offA[m][1]);
#pragma unroll
    for (int n = 0; n < 2; ++n) bfr[n] = *(const bf16x8*)(Lc + offB[n][1]);
    if (doStage) { stageInst(nst, 3); stageInst(nst, 4); stageInst(nst, 5); }
    __builtin_amdgcn_s_barrier();
    asm volatile("s_waitcnt lgkmcnt(0)" ::: "memory");
    __builtin_amdgcn_sched_barrier(0);
    __builtin_amdgcn_s_setprio(1);
#pragma unroll
    for (int m = 0; m < 8; ++m)
#pragma unroll
      for (int n = 0; n < 2; ++n)
        acc[m][n] = __builtin_amdgcn_mfma_f32_16x16x32_bf16(af[m], bfr[n],
                                                            acc[m][n], 0, 0, 0);
    __builtin_amdgcn_s_setprio(0);
#pragma unroll
    for (int i = 0; i < 6; ++i) srcp[i] += BK;
    // counted wait: guarantees NEXT tile's 6 loads landed; newest 6 stay in flight
    if (t < NT - 2) asm volatile("s_waitcnt vmcnt(6)" ::: "memory");
    else            asm volatile("s_waitcnt vmcnt(0)" ::: "memory");
    __builtin_amdgcn_s_barrier();

    cur = (cur + 1 >= 3) ? 0 : cur + 1;
  }

  // epilogue: C/D layout col=lane&15, row=(lane>>4)*4+reg; fuse bias superposition
  const int i0 = sidx[2 * b], i1 = sidx[2 * b + 1];
  const float p0 = sprob[2 * b], p1 = sprob[2 * b + 1];
  const int rq = q * 4;
  float* Ob = out + (size_t)b * D * D;
#pragma unroll
  for (int n = 0; n < 2; ++n) {
    const int colg = n0 + wn + n * 16 + fm;
    const float bs = p0 * bias[i0 * D + colg] + p1 * bias[i1 * D + colg];
#pragma unroll
    for (int m = 0; m < 8; ++m) {
      const int rowb = m0 + wm + m * 16 + rq;
#pragma unroll
      for (int r = 0; r < 4; ++r)
        Ob[(size_t)(rowb + r) * D + colg] = acc[m][n][r] + bs;
    }
  }
}

extern "C" void kernel_launch(void* const* d_in, const int* in_sizes, int n_in,
                              void* d_out, int out_size, void* d_ws, size_t ws_size,
                              hipStream_t stream) {
  const float* tensor = (const float*)d_in[0];   // (2,2048,16,128) fp32
  const int*   sidx   = (const int*)d_in[1];     // (2,2) int32
  const float* sprob  = (const float*)d_in[2];   // (2,2) fp32
  const float* weight = (const float*)d_in[3];   // (16,2048,2048) fp32
  const float* bias   = (const float*)d_in[4];   // (16,2048) fp32
  float* out = (float*)d_out;                    // (2,2048,2048) fp32

  u16* xb = (u16*)d_ws;                          // (2,2048,2048) bf16, 16 MB
  u16* wt = xb + (size_t)BATCH * D * D;          // (2,2048,2048) bf16, 16 MB

  static bool inited = false;
  if (!inited) {
    (void)hipFuncSetAttribute((const void*)gemm_kernel,
                              hipFuncAttributeMaxDynamicSharedMemorySize,
                              3 * BUFSZ * 2);
    inited = true;
  }

  hipLaunchKernelGGL(prep_x_kernel, dim3((BATCH * D * D) / (256 * 8)), dim3(256), 0, stream,
                     tensor, xb);
  hipLaunchKernelGGL(prep_w_kernel, dim3(D / 256, D / 32, BATCH), dim3(256), 0, stream,
                     weight, sidx, sprob, wt);
  hipLaunchKernelGGL(gemm_kernel, dim3(D / BN, D / BM, BATCH), dim3(512),
                     3 * BUFSZ * 2, stream, xb, wt, bias, sidx, sprob, out);
}

// Round 2
// 382.360 us; speedup vs baseline: 1.0171x; 1.0171x over previous
//
#include <hip/hip_runtime.h>

typedef unsigned int u32;
typedef unsigned short u16;
typedef __bf16 bf16x8 __attribute__((ext_vector_type(8)));
typedef float f32x4 __attribute__((ext_vector_type(4)));

#define D 2048           // D_IN == D_MODEL == S == 2048
#define BATCH 2
#define BM 256
#define BN 128
#define BK 64
#define NT (D / BK)          // 32 K-tiles
#define ABUF (BM * BK)       // 16384 u16 = 32 KB
#define BBUF (BN * BK)       // 8192  u16 = 16 KB
#define BUFSZ (ABUF + BBUF)  // 24576 u16 = 48 KB per buffer, x3 = 144 KB

// ---------- helpers ----------
__device__ __forceinline__ u32 bf16rne(float f) {
  u32 u = __builtin_bit_cast(u32, f);
  return (u + 0x7fffu + ((u >> 16) & 1u)) >> 16;
}
__device__ __forceinline__ u32 pk2(float lo, float hi) {
  return bf16rne(lo) | (bf16rne(hi) << 16);
}
__device__ __forceinline__ void async16(const u16* g, u16* l) {
  __builtin_amdgcn_global_load_lds(
      (const __attribute__((address_space(1))) void*)g,
      (__attribute__((address_space(3))) void*)l, 16, 0, 0);
}

// ---------- merged prep: blocks [0,4096) convert x; blocks [4096,5120) build wt ----------
// prep_x: xb = bf16(x), contiguous, 8 elems/thread.
// prep_w: wt[b][n][k] = bf16(p0*W[i0][k][n] + p1*W[i1][k][n])  (transpose + superpose)
__global__ void __launch_bounds__(256) prep_kernel(const float* __restrict__ x,
                                                   u16* __restrict__ xb,
                                                   const float* __restrict__ W,
                                                   const int* __restrict__ sidx,
                                                   const float* __restrict__ sprob,
                                                   u16* __restrict__ wt) {
  if (blockIdx.x < 4096) {
    size_t t = (size_t)blockIdx.x * 256 + threadIdx.x;
    const float4* x4 = (const float4*)x;
    float4 a = x4[2 * t], c = x4[2 * t + 1];
    ((uint4*)xb)[t] = make_uint4(pk2(a.x, a.y), pk2(a.z, a.w),
                                 pk2(c.x, c.y), pk2(c.z, c.w));
  } else {
    const int bid = blockIdx.x - 4096;       // decode old (8, 64, 2) grid
    const int b = bid >> 9;
    const int n = (bid & 7) * 256 + threadIdx.x;
    const int k0 = ((bid >> 3) & 63) * 32;
    const int i0 = sidx[2 * b], i1 = sidx[2 * b + 1];
    const float p0 = sprob[2 * b], p1 = sprob[2 * b + 1];
    const float* w0 = W + ((size_t)i0 * D + k0) * D + n;
    const float* w1 = W + ((size_t)i1 * D + k0) * D + n;
    u32 r[16];
#pragma unroll
    for (int kk = 0; kk < 16; ++kk) {
      float a0 = w0[(size_t)(2 * kk) * D],     c0 = w1[(size_t)(2 * kk) * D];
      float a1 = w0[(size_t)(2 * kk + 1) * D], c1 = w1[(size_t)(2 * kk + 1) * D];
      r[kk] = pk2(p0 * a0 + p1 * c0, p0 * a1 + p1 * c1);
    }
    uint4* dst = (uint4*)(wt + ((size_t)b * D + n) * D + k0);
#pragma unroll
    for (int qq = 0; qq < 4; ++qq)
      dst[qq] = make_uint4(r[4 * qq], r[4 * qq + 1], r[4 * qq + 2], r[4 * qq + 3]);
  }
}

// ---------- kernel 3: out[b] = xb[b] @ wt[b]^T + bsel[b] ----------
// 256x128 tile, BK=64, 512 threads = 8 waves (4M x 2N), per-wave 64x64 output.
// Triple-buffered LDS (144 KB), counted vmcnt(6) (never drained in-loop),
// XOR-swizzled k-chunks (pre-swizzled global source + linear global_load_lds
// dest + swizzled ds_read), setprio around MFMA, XCD-aware block swizzle.
// 3 barriers per K-tile: intra-iteration hazards don't exist (reads hit cur,
// stages hit nst != cur); only the end-of-iteration barrier is correctness-bearing.
__global__ void __launch_bounds__(512, 2)
gemm_kernel(const u16* __restrict__ xb, const u16* __restrict__ wt,
            const float* __restrict__ bias, const int* __restrict__ sidx,
            const float* __restrict__ sprob, float* __restrict__ out) {
  extern __shared__ __align__(16) u16 LL[];

  // XCD swizzle: consecutive blockIdx round-robin XCDs; give each XCD a
  // contiguous swz-chunk => 2 A-panel groups per XCD (A is the x16-reused operand).
  const int fid = blockIdx.x;                  // 0..255
  const int swz = (fid & 7) * 32 + (fid >> 3); // bijective (256 % 8 == 0)
  const int b   = swz >> 7;                    // batch
  const int rem = swz & 127;
  const int m0 = (rem >> 4) * BM;              // 8 m-blocks
  const int n0 = (rem & 15) * BN;              // 16 n-blocks (consecutive swz share A-panel)

  const int tid  = threadIdx.x;
  const int lane = tid & 63;
  const int wid  = tid >> 6;
  const int wm = (wid >> 1) * 64;   // 4 wave-rows over 256 m
  const int wn = (wid & 1) * 64;    // 2 wave-cols over 128 n
  const int fm = lane & 15;
  const int q  = lane >> 4;         // 16B k-chunk index within a 32-k plane

  const u16* Ab = xb + (size_t)b * D * D;
  const u16* Bb = wt + (size_t)b * D * D;

  // staging: inst i covers granules g = i*512 + tid; row = g>>3, phys slot = g&7.
  // LDS dest is linear; the XOR swizzle is applied on the SOURCE k-chunk (m173).
  const int srow  = tid >> 3;                   // row within 64-row inst stripe
  const int sslot = (tid & 7) ^ (srow & 7);     // pre-swizzled logical k-chunk
  const u16* srcp[6];
#pragma unroll
  for (int i = 0; i < 4; ++i)
    srcp[i] = Ab + (size_t)(m0 + i * 64 + srow) * D + sslot * 8;
#pragma unroll
  for (int i = 0; i < 2; ++i)
    srcp[4 + i] = Bb + (size_t)(n0 + i * 64 + srow) * D + sslot * 8;

  const int wuni = (tid & ~63) * 8;  // wave-uniform LDS granule base (elems)

  auto stageInst = [&](int buf, int i) {
    async16(srcp[i], LL + buf * BUFSZ + i * 4096 + wuni);
  };

  // fragment read offsets (elements), XOR-swizzled to match the staged layout
  int offA[4][2], offB[4][2];
#pragma unroll
  for (int m = 0; m < 4; ++m) {
    const int row = wm + m * 16 + fm;
#pragma unroll
    for (int ks = 0; ks < 2; ++ks)
      offA[m][ks] = row * 64 + (((ks * 4 + q) ^ (row & 7)) * 8);
  }
#pragma unroll
  for (int n = 0; n < 4; ++n) {
    const int row = wn + n * 16 + fm;
#pragma unroll
    for (int ks = 0; ks < 2; ++ks)
      offB[n][ks] = ABUF + row * 64 + (((ks * 4 + q) ^ (row & 7)) * 8);
  }

  f32x4 acc[4][4] = {};

  // prologue: stage tiles 0,1 into bufs 0,1; wait only for tile 0 (vmcnt(6))
#pragma unroll
  for (int i = 0; i < 6; ++i) stageInst(0, i);
#pragma unroll
  for (int i = 0; i < 6; ++i) srcp[i] += BK;
#pragma unroll
  for (int i = 0; i < 6; ++i) stageInst(1, i);
#pragma unroll
  for (int i = 0; i < 6; ++i) srcp[i] += BK;
  asm volatile("s_waitcnt vmcnt(6)" ::: "memory");
  __builtin_amdgcn_s_barrier();

  int cur = 0;
#pragma unroll 1
  for (int t = 0; t < NT; ++t) {
    const u16* Lc = LL + cur * BUFSZ;
    int nst = cur + 2; if (nst >= 3) nst -= 3;
    const bool doStage = (t + 2 < NT);

    bf16x8 af[4], bfr[4];

    // ---- phase 0 (ks = 0) ----
#pragma unroll
    for (int m = 0; m < 4; ++m) af[m]  = *(const bf16x8*)(Lc + offA[m][0]);
#pragma unroll
    for (int n = 0; n < 4; ++n) bfr[n] = *(const bf16x8*)(Lc + offB[n][0]);
    if (doStage) { stageInst(nst, 0); stageInst(nst, 1); stageInst(nst, 2); }
    __builtin_amdgcn_s_barrier();
    asm volatile("s_waitcnt lgkmcnt(0)" ::: "memory");
    __builtin_amdgcn_sched_barrier(0);
    __builtin_amdgcn_s_setprio(1);
#pragma unroll
    for (int m = 0; m < 4; ++m)
#pragma unroll
      for (int n = 0; n < 4; ++n)
        acc[m][n] = __builtin_amdgcn_mfma_f32_16x16x32_bf16(af[m], bfr[n],
                                                            acc[m][n], 0, 0, 0);
    __builtin_amdgcn_s_setprio(0);

    // ---- phase 1 (ks = 1), no barrier against phase 0: no intra-iter hazard ----
#pragma unroll
    for (int m = 0; m < 4; ++m) af[m]  = *(const bf16x8*)(Lc + offA[m][1]);
#pragma unroll
    for (int n = 0; n < 4; ++n) bfr[n] = *(const bf16x8*)(Lc + offB[n][1]);
    if (doStage) { stageInst(nst, 3); stageInst(nst, 4); stageInst(nst, 5); }
    __builtin_amdgcn_s_barrier();
    asm volatile("s_waitcnt lgkmcnt(0)" ::: "memory");
    __builtin_amdgcn_sched_barrier(0);
    __builtin_amdgcn_s_setprio(1);
#pragma unroll
    for (int m = 0; m < 4; ++m)
#pragma unroll
      for (int n = 0; n < 4; ++n)
        acc[m][n] = __builtin_amdgcn_mfma_f32_16x16x32_bf16(af[m], bfr[n],
                                                            acc[m][n], 0, 0, 0);
    __builtin_amdgcn_s_setprio(0);
#pragma unroll
    for (int i = 0; i < 6; ++i) srcp[i] += BK;
    // counted wait: guarantees NEXT tile's 6 loads landed; newest 6 stay in flight
    if (t < NT - 2) asm volatile("s_waitcnt vmcnt(6)" ::: "memory");
    else            asm volatile("s_waitcnt vmcnt(0)" ::: "memory");
    __builtin_amdgcn_s_barrier();

    cur = (cur + 1 >= 3) ? 0 : cur + 1;
  }

  // epilogue: C/D layout col=lane&15, row=(lane>>4)*4+reg; fuse bias superposition
  const int i0 = sidx[2 * b], i1 = sidx[2 * b + 1];
  const float p0 = sprob[2 * b], p1 = sprob[2 * b + 1];
  const int rq = q * 4;
  float* Ob = out + (size_t)b * D * D;
#pragma unroll
  for (int n = 0; n < 4; ++n) {
    const int colg = n0 + wn + n * 16 + fm;
    const float bs = p0 * bias[i0 * D + colg] + p1 * bias[i1 * D + colg];
#pragma unroll
    for (int m = 0; m < 4; ++m) {
      const int rowb = m0 + wm + m * 16 + rq;
#pragma unroll
      for (int r = 0; r < 4; ++r)
        Ob[(size_t)(rowb + r) * D + colg] = acc[m][n][r] + bs;
    }
  }
}

extern "C" void kernel_launch(void* const* d_in, const int* in_sizes, int n_in,
                              void* d_out, int out_size, void* d_ws, size_t ws_size,
                              hipStream_t stream) {
  const float* tensor = (const float*)d_in[0];   // (2,2048,16,128) fp32
  const int*   sidx   = (const int*)d_in[1];     // (2,2) int32
  const float* sprob  = (const float*)d_in[2];   // (2,2) fp32
  const float* weight = (const float*)d_in[3];   // (16,2048,2048) fp32
  const float* bias   = (const float*)d_in[4];   // (16,2048) fp32
  float* out = (float*)d_out;                    // (2,2048,2048) fp32

  u16* xb = (u16*)d_ws;                          // (2,2048,2048) bf16, 16 MB
  u16* wt = xb + (size_t)BATCH * D * D;          // (2,2048,2048) bf16, 16 MB

  static bool inited = false;
  if (!inited) {
    (void)hipFuncSetAttribute((const void*)gemm_kernel,
                              hipFuncAttributeMaxDynamicSharedMemorySize,
                              3 * BUFSZ * 2);
    inited = true;
  }

  hipLaunchKernelGGL(prep_kernel, dim3(4096 + 1024), dim3(256), 0, stream,
                     tensor, xb, weight, sidx, sprob, wt);
  hipLaunchKernelGGL(gemm_kernel, dim3(256), dim3(512),
                     3 * BUFSZ * 2, stream, xb, wt, bias, sidx, sprob, out);
}